// Round 1
// 377.999 us; speedup vs baseline: 1.0311x; 1.0311x over previous
//
#include <hip/hip_runtime.h>
#include <hip/hip_bf16.h>

// LightAttention: Z = softmax_n(Q/d4) @ [ softmax_n(K/d4)^T @ V ]
// Folded: E=exp(Q/d4), F=exp(K/d4), Sq/Sk col-sums over n,
//   Bm[d,e] = sum_n F[n,d] V[n,e];  Ct[e,d] = Bm[d,e]/(Sq[d]Sk[d]);  Z = E @ Ct^T.
//
// Round-5 structure (latency-bound fix):
//  - proj_q / proj_kv / z_gemm: single-barrier-per-K-step pipeline.
//    B-operand (L2-resident Wt / Ct) loaded per-lane DIRECT to MFMA fragment
//    registers, double-buffered, issued 1 step ahead -> stays in flight across
//    the barrier (no vmcnt drain; compiler inserts counted vmcnt at use).
//    A-operand (X fp32 / Eq bf16) via double-buffered LDS, reg-prefetched
//    2 steps ahead; barrier = s_waitcnt lgkmcnt(0) + raw s_barrier only.
//    Each wave owns a distinct 64-col B-slice (no duplicate B traffic).
//  - bm_gemm: split-K 2 -> 4 (2 blocks/CU instead of 1; ws_size-guarded),
//    stage(next) issued BEFORE ds_read+MFMA, single vmcnt(0) barrier per step.

typedef __bf16 bf16_t;
typedef __attribute__((ext_vector_type(8))) __bf16 bf16x8;
typedef __attribute__((ext_vector_type(4))) float f32x4;

#define MFMA_BF16 __builtin_amdgcn_mfma_f32_16x16x32_bf16

__device__ inline void async_ld16(const void* g, void* l) {
  __builtin_amdgcn_global_load_lds(
      (const __attribute__((address_space(1))) void*)g,
      (__attribute__((address_space(3))) void*)l, 16, 0, 0);
}

#define INV_D4 0.2102241038134287f  // 1 / 512^0.25

// Barrier that does NOT drain vmcnt: in-flight register global loads survive.
#define BAR_LGKM()                                        \
  do {                                                    \
    asm volatile("s_waitcnt lgkmcnt(0)" ::: "memory");    \
    __builtin_amdgcn_s_barrier();                         \
  } while (0)

// Barrier for global_load_lds staging (bm_gemm): drain vm + lgkm.
#define BAR_VM_LGKM()                                             \
  do {                                                            \
    asm volatile("s_waitcnt vmcnt(0) lgkmcnt(0)" ::: "memory");   \
    __builtin_amdgcn_s_barrier();                                 \
  } while (0)

__device__ inline void cvt_store(bf16_t* dst, int c0, int ar, const float4& f0,
                                 const float4& f1, const float4& f2,
                                 const float4& f3) {
  bf16x8 p0, p1;
  p0[0] = (__bf16)f0.x; p0[1] = (__bf16)f0.y; p0[2] = (__bf16)f0.z; p0[3] = (__bf16)f0.w;
  p0[4] = (__bf16)f1.x; p0[5] = (__bf16)f1.y; p0[6] = (__bf16)f1.z; p0[7] = (__bf16)f1.w;
  p1[0] = (__bf16)f2.x; p1[1] = (__bf16)f2.y; p1[2] = (__bf16)f2.z; p1[3] = (__bf16)f2.w;
  p1[4] = (__bf16)f3.x; p1[5] = (__bf16)f3.y; p1[6] = (__bf16)f3.z; p1[7] = (__bf16)f3.w;
  ((bf16x8*)dst)[c0 * 128 + ar] = p0;
  ((bf16x8*)dst)[(c0 + 1) * 128 + ar] = p1;
}

// ---------------- W transpose+convert: W[in][out] f32 -> Wt[out][in] bf16 ----
__global__ __launch_bounds__(256) void wt_kernel(
    const float* __restrict__ Wq, const float* __restrict__ Wk,
    const float* __restrict__ Wv, bf16_t* __restrict__ Wt) {
  const int z = blockIdx.z;
  const float* W = (z == 0) ? Wq : (z == 1) ? Wk : Wv;
  bf16_t* O = Wt + (size_t)z * 262144;
  __shared__ __align__(16) bf16_t tile[64 * 72];
  const int t = threadIdx.x;
  const int r = t >> 2;
  const int c4 = (t & 3) * 16;
  const int in0 = blockIdx.x * 64, out0 = blockIdx.y * 64;
  const float* src = W + (size_t)(in0 + r) * 512 + out0 + c4;
#pragma unroll
  for (int i = 0; i < 4; ++i) {
    float4 f = ((const float4*)src)[i];
    tile[(c4 + i * 4 + 0) * 72 + r] = (__bf16)f.x;
    tile[(c4 + i * 4 + 1) * 72 + r] = (__bf16)f.y;
    tile[(c4 + i * 4 + 2) * 72 + r] = (__bf16)f.z;
    tile[(c4 + i * 4 + 3) * 72 + r] = (__bf16)f.w;
  }
  __syncthreads();
  bf16x8* dst = (bf16x8*)(O + (size_t)(out0 + r) * 512 + in0 + c4);
  const bf16x8* s = (const bf16x8*)(tile + r * 72 + c4);
  dst[0] = s[0];
  dst[1] = s[1];
}

// ---------------- proj_q: Eq[n][d]=exp((Xq@Wq+b)/d4), 128x256 tiles ---------
// A = Xq rows via LDS (dbuf, reg prefetch 2 ahead); B = Wt rows DIRECT to regs
// (dbuf, 1 ahead).  Per wave: full 128 m-rows x own 64 n-cols.
__global__ __launch_bounds__(256, 2) void proj_q(
    const float* __restrict__ Xq, const bf16_t* __restrict__ Wt,
    const float* __restrict__ bias, bf16_t* __restrict__ Eq,
    float* __restrict__ Sq) {
  __shared__ __align__(16) bf16_t Xs[2][4096];  // [buf][chunk(4)][row(128)]

  const int t = threadIdx.x;
  const int lane = t & 63, w = t >> 6;
  const int quad = lane >> 4, l15 = lane & 15;
  const int m0 = blockIdx.x * 128;
  const int n0 = blockIdx.y * 256 + w * 64;  // per-wave col base

  f32x4 acc[8][4];
  const f32x4 zero4 = {0.f, 0.f, 0.f, 0.f};
#pragma unroll
  for (int i = 0; i < 8; ++i)
#pragma unroll
    for (int j = 0; j < 4; ++j) acc[i][j] = zero4;

  const int ar = t >> 1;
  const int c0 = (t & 1) * 2;
  const float* abase = Xq + (size_t)(m0 + ar) * 512 + (t & 1) * 16;
  const bf16_t* wbase = Wt + (size_t)(n0 + l15) * 512 + quad * 8;

  float4 fb[2][4];   // X fp32 prefetch, 2 steps deep
  bf16x8 wr[2][4];   // W fragment regs, 1 step deep

  {
    const float4* p = (const float4*)abase;
    fb[1][0] = p[0]; fb[1][1] = p[1]; fb[1][2] = p[2]; fb[1][3] = p[3];
  }
#pragma unroll
  for (int ni = 0; ni < 4; ++ni)
    wr[0][ni] = *(const bf16x8*)(wbase + ni * 8192);
  {
    const float4* p = (const float4*)(abase + 32);
    fb[0][0] = p[0]; fb[0][1] = p[1]; fb[0][2] = p[2]; fb[0][3] = p[3];
  }
  cvt_store(Xs[0], c0, ar, fb[1][0], fb[1][1], fb[1][2], fb[1][3]);
  {
    const float4* p = (const float4*)(abase + 64);
    fb[1][0] = p[0]; fb[1][1] = p[1]; fb[1][2] = p[2]; fb[1][3] = p[3];
  }
  BAR_LGKM();

#pragma unroll
  for (int ks = 0; ks < 16; ++ks) {
    const int p = ks & 1;
    bf16x8 af[8];
#pragma unroll
    for (int mi = 0; mi < 8; ++mi)
      af[mi] = ((const bf16x8*)Xs[p])[quad * 128 + mi * 16 + l15];
    if (ks < 15) {
      cvt_store(Xs[p ^ 1], c0, ar, fb[p][0], fb[p][1], fb[p][2], fb[p][3]);
#pragma unroll
      for (int ni = 0; ni < 4; ++ni)
        wr[p ^ 1][ni] = *(const bf16x8*)(wbase + ni * 8192 + (ks + 1) * 32);
      if (ks < 13) {
        const float4* pp = (const float4*)(abase + (ks + 3) * 32);
        fb[p][0] = pp[0]; fb[p][1] = pp[1]; fb[p][2] = pp[2]; fb[p][3] = pp[3];
      }
    }
#pragma unroll
    for (int mi = 0; mi < 8; ++mi)
#pragma unroll
      for (int ni = 0; ni < 4; ++ni)
        acc[mi][ni] = MFMA_BF16(af[mi], wr[p][ni], acc[mi][ni], 0, 0, 0);
    if (ks < 15) BAR_LGKM();
  }

  const int b = m0 >> 12;
  float cs[4] = {0.f, 0.f, 0.f, 0.f};
#pragma unroll
  for (int ni = 0; ni < 4; ++ni) {
    const int col = n0 + ni * 16 + l15;
    const float bv_ = bias[col];
#pragma unroll
    for (int mi = 0; mi < 8; ++mi)
#pragma unroll
      for (int r = 0; r < 4; ++r) {
        const int row = m0 + mi * 16 + quad * 4 + r;
        float v = __expf((acc[mi][ni][r] + bv_) * INV_D4);
        Eq[(size_t)row * 512 + col] = (bf16_t)v;
        cs[ni] += v;
      }
  }
#pragma unroll
  for (int ni = 0; ni < 4; ++ni) {
    cs[ni] += __shfl_xor(cs[ni], 16);
    cs[ni] += __shfl_xor(cs[ni], 32);
  }
  if (lane < 16) {
#pragma unroll
    for (int ni = 0; ni < 4; ++ni)
      atomicAdd(&Sq[b * 512 + n0 + ni * 16 + lane], cs[ni]);
  }
}

// ---------------- proj_kv: Ft/Vt[b][d][n], 256(d)x128(n) tiles --------------
// A = Wt rows DIRECT to regs (per wave: own 64 d-rows); B = X rows via LDS.
__global__ __launch_bounds__(256, 2) void proj_kv(
    const float* __restrict__ xk, const float* __restrict__ xv,
    const bf16_t* __restrict__ Wt, const float* __restrict__ bk,
    const float* __restrict__ bv, bf16_t* __restrict__ Ft,
    bf16_t* __restrict__ Vt) {
  const int z = blockIdx.z + 1;  // 1=K, 2=V
  const float* X = (z == 1) ? xk : xv;
  const float* bias = (z == 1) ? bk : bv;
  const bf16_t* W = Wt + (size_t)z * 262144;
  bf16_t* Out = (z == 1) ? Ft : Vt;
  const bool expm = (z == 1);

  __shared__ __align__(16) bf16_t Xs[2][4096];

  const int t = threadIdx.x;
  const int lane = t & 63, w = t >> 6;
  const int quad = lane >> 4, l15 = lane & 15;
  const int ng = blockIdx.x * 128;             // global n over 32768
  const int d0 = blockIdx.y * 256 + w * 64;    // per-wave d base

  f32x4 acc[4][8];
  const f32x4 zero4 = {0.f, 0.f, 0.f, 0.f};
#pragma unroll
  for (int i = 0; i < 4; ++i)
#pragma unroll
    for (int j = 0; j < 8; ++j) acc[i][j] = zero4;

  const int ar = t >> 1;
  const int c0 = (t & 1) * 2;
  const float* bbase = X + (size_t)(ng + ar) * 512 + (t & 1) * 16;
  const bf16_t* wbase = W + (size_t)(d0 + l15) * 512 + quad * 8;

  float4 fb[2][4];
  bf16x8 wr[2][4];

  {
    const float4* p = (const float4*)bbase;
    fb[1][0] = p[0]; fb[1][1] = p[1]; fb[1][2] = p[2]; fb[1][3] = p[3];
  }
#pragma unroll
  for (int mi = 0; mi < 4; ++mi)
    wr[0][mi] = *(const bf16x8*)(wbase + mi * 8192);
  {
    const float4* p = (const float4*)(bbase + 32);
    fb[0][0] = p[0]; fb[0][1] = p[1]; fb[0][2] = p[2]; fb[0][3] = p[3];
  }
  cvt_store(Xs[0], c0, ar, fb[1][0], fb[1][1], fb[1][2], fb[1][3]);
  {
    const float4* p = (const float4*)(bbase + 64);
    fb[1][0] = p[0]; fb[1][1] = p[1]; fb[1][2] = p[2]; fb[1][3] = p[3];
  }
  BAR_LGKM();

#pragma unroll
  for (int ks = 0; ks < 16; ++ks) {
    const int p = ks & 1;
    bf16x8 bx[8];
#pragma unroll
    for (int ni = 0; ni < 8; ++ni)
      bx[ni] = ((const bf16x8*)Xs[p])[quad * 128 + ni * 16 + l15];
    if (ks < 15) {
      cvt_store(Xs[p ^ 1], c0, ar, fb[p][0], fb[p][1], fb[p][2], fb[p][3]);
#pragma unroll
      for (int mi = 0; mi < 4; ++mi)
        wr[p ^ 1][mi] = *(const bf16x8*)(wbase + mi * 8192 + (ks + 1) * 32);
      if (ks < 13) {
        const float4* pp = (const float4*)(bbase + (ks + 3) * 32);
        fb[p][0] = pp[0]; fb[p][1] = pp[1]; fb[p][2] = pp[2]; fb[p][3] = pp[3];
      }
    }
#pragma unroll
    for (int mi = 0; mi < 4; ++mi)
#pragma unroll
      for (int ni = 0; ni < 8; ++ni)
        acc[mi][ni] = MFMA_BF16(wr[p][mi], bx[ni], acc[mi][ni], 0, 0, 0);
    if (ks < 15) BAR_LGKM();
  }

  const int b = ng >> 12;
  const int nl0 = (ng & 4095);
#pragma unroll
  for (int mi = 0; mi < 4; ++mi)
#pragma unroll
    for (int r = 0; r < 4; ++r) {
      const int d = d0 + mi * 16 + quad * 4 + r;
      const float bv_ = bias[d];
      bf16_t* rowp = Out + (size_t)b * 2097152 + (size_t)d * 4096 + nl0;
#pragma unroll
      for (int ni = 0; ni < 8; ++ni) {
        float v = acc[mi][ni][r] + bv_;
        if (expm) v = __expf(v * INV_D4);
        rowp[ni * 16 + l15] = (bf16_t)v;
      }
    }
}

// ---------------- Sk[b*512+d] = sum_n Ft[b][d][n] (row sums) ----------------
__global__ __launch_bounds__(256) void sk_kernel(const bf16_t* __restrict__ Ft,
                                                 float* __restrict__ Sk) {
  const int row = blockIdx.x * 4 + (threadIdx.x >> 6);
  const int lane = threadIdx.x & 63;
  const bf16x8* p = (const bf16x8*)(Ft + (size_t)row * 4096) + lane;
  float s = 0.f;
#pragma unroll
  for (int j = 0; j < 8; ++j) {
    bf16x8 v = p[j * 64];
#pragma unroll
    for (int e = 0; e < 8; ++e) s += (float)v[e];
  }
#pragma unroll
  for (int m = 1; m <= 32; m <<= 1) s += __shfl_xor(s, m);
  if (lane == 0) Sk[row] = s;
}

// ---------------- Bm GEMM: Bmp[s][b][d][e] = sum_{n in slice} Ft[d][n]Vt[e][n]
// Split-K S (2 or 4), stage(next) before compute, 1 vmcnt(0) barrier/step.
__global__ __launch_bounds__(256, 2) void bm_gemm(
    const bf16_t* __restrict__ Ft, const bf16_t* __restrict__ Vt,
    float* __restrict__ Bmp, int S) {
  const int b = blockIdx.z / S;
  const int s = blockIdx.z - b * S;
  const int d0 = blockIdx.x * 128;
  const int e0 = blockIdx.y * 128;
  const bf16_t* A = Ft + (size_t)b * 2097152;
  const bf16_t* B = Vt + (size_t)b * 2097152;
  float* out = Bmp + ((size_t)s * 8 + b) * 262144;

  __shared__ __align__(16) bf16_t As[2][4096];
  __shared__ __align__(16) bf16_t Bs[2][4096];

  const int t = threadIdx.x;
  const int lane = t & 63, w = t >> 6;
  const int quad = lane >> 4, l15 = lane & 15;
  const int m_off = (w & 1) * 64, n_off = (w >> 1) * 64;

  const int kper = 4096 / S;
  const int KS = kper >> 5;
  const int kbase = s * kper;

  f32x4 acc[4][4];
  const f32x4 zero4 = {0.f, 0.f, 0.f, 0.f};
#pragma unroll
  for (int i = 0; i < 4; ++i)
#pragma unroll
    for (int j = 0; j < 4; ++j) acc[i][j] = zero4;

  const int j0 = w * 2;
  auto stage = [&](int buf, int ks) {
#pragma unroll
    for (int i = 0; i < 2; ++i) {
      const int j = j0 + i;
      const int k8 = j >> 1;
      const int r = ((j & 1) << 6) + lane;
      const int kel = kbase + ks * 32 + k8 * 8;
      async_ld16(A + (size_t)(d0 + r) * 4096 + kel, &As[buf][j * 512]);
      async_ld16(B + (size_t)(e0 + r) * 4096 + kel, &Bs[buf][j * 512]);
    }
  };

  stage(0, 0);
  BAR_VM_LGKM();

  for (int ks = 0; ks < KS; ++ks) {
    const int p = ks & 1;
    if (ks + 1 < KS) stage(p ^ 1, ks + 1);
    bf16x8 af[4], bfr[4];
#pragma unroll
    for (int mi = 0; mi < 4; ++mi)
      af[mi] = ((const bf16x8*)As[p])[quad * 128 + m_off + mi * 16 + l15];
#pragma unroll
    for (int ni = 0; ni < 4; ++ni)
      bfr[ni] = ((const bf16x8*)Bs[p])[quad * 128 + n_off + ni * 16 + l15];
#pragma unroll
    for (int mi = 0; mi < 4; ++mi)
#pragma unroll
      for (int ni = 0; ni < 4; ++ni)
        acc[mi][ni] = MFMA_BF16(af[mi], bfr[ni], acc[mi][ni], 0, 0, 0);
    if (ks + 1 < KS) BAR_VM_LGKM();
  }

#pragma unroll
  for (int mi = 0; mi < 4; ++mi)
#pragma unroll
    for (int ni = 0; ni < 4; ++ni) {
      const int ecol = e0 + n_off + ni * 16 + l15;
#pragma unroll
      for (int r = 0; r < 4; ++r) {
        const int drow = d0 + m_off + mi * 16 + quad * 4 + r;
        out[(size_t)drow * 512 + ecol] = acc[mi][ni][r];
      }
    }
}

// ---------------- scale + reduce partials + transpose -----------------------
// Ct[b][e][d] = (sum_s Bmp[s])[b][d][e] / (Sq[b][d]*Sk[b][d])
__global__ __launch_bounds__(256) void scale_kernel(
    const float* __restrict__ Bmp, const float* __restrict__ Sq,
    const float* __restrict__ Sk, bf16_t* __restrict__ Ct, int S) {
  const int b = blockIdx.z;
  const int d0 = blockIdx.x * 64, e0 = blockIdx.y * 64;
  __shared__ __align__(16) bf16_t tile[64 * 72];
  const int t = threadIdx.x;
  const int r = t >> 2;
  const int c4 = (t & 3) * 16;
  const int d = d0 + r;
  const float f = 1.0f / (Sq[b * 512 + d] * Sk[b * 512 + d]);
  const float* p0 = Bmp + (size_t)b * 262144 + (size_t)d * 512 + e0 + c4;
#pragma unroll
  for (int i = 0; i < 4; ++i) {
    float sx = 0.f, sy = 0.f, sz = 0.f, sw = 0.f;
    for (int sp = 0; sp < S; ++sp) {
      float4 v = ((const float4*)(p0 + (size_t)sp * 2097152))[i];
      sx += v.x; sy += v.y; sz += v.z; sw += v.w;
    }
    tile[(c4 + i * 4 + 0) * 72 + r] = (__bf16)(sx * f);
    tile[(c4 + i * 4 + 1) * 72 + r] = (__bf16)(sy * f);
    tile[(c4 + i * 4 + 2) * 72 + r] = (__bf16)(sz * f);
    tile[(c4 + i * 4 + 3) * 72 + r] = (__bf16)(sw * f);
  }
  __syncthreads();
  bf16x8* dst = (bf16x8*)(Ct + (size_t)b * 262144 + (size_t)(e0 + r) * 512 + d0 + c4);
  const bf16x8* sptr = (const bf16x8*)(tile + r * 72 + c4);
  dst[0] = sptr[0];
  dst[1] = sptr[1];
}

// ---------------- Z GEMM: Z[row,e]=sum_d Eq[row,d]*Ct[b][e][d], 128x256 -----
// A = Eq rows via LDS (reg-staged 2 ahead); B = Ct rows DIRECT to regs.
__global__ __launch_bounds__(256, 2) void z_gemm(
    const bf16_t* __restrict__ Eq, const bf16_t* __restrict__ Ct,
    float* __restrict__ out) {
  __shared__ __align__(16) bf16_t Xs[2][4096];

  const int t = threadIdx.x;
  const int lane = t & 63, w = t >> 6;
  const int quad = lane >> 4, l15 = lane & 15;
  const int m0 = blockIdx.x * 128;
  const int n0 = blockIdx.y * 256 + w * 64;
  const int batch = m0 >> 12;
  const bf16_t* Bt = Ct + (size_t)batch * 262144;

  f32x4 acc[8][4];
  const f32x4 zero4 = {0.f, 0.f, 0.f, 0.f};
#pragma unroll
  for (int i = 0; i < 8; ++i)
#pragma unroll
    for (int j = 0; j < 4; ++j) acc[i][j] = zero4;

  const int ar = t >> 1;
  const int c0 = (t & 1) * 2;
  const bf16_t* abase = Eq + (size_t)(m0 + ar) * 512 + (t & 1) * 16;
  const bf16_t* wbase = Bt + (size_t)(n0 + l15) * 512 + quad * 8;

  bf16x8 eb[2][2];
  bf16x8 wr[2][4];

  eb[1][0] = *(const bf16x8*)abase;
  eb[1][1] = *(const bf16x8*)(abase + 8);
#pragma unroll
  for (int ni = 0; ni < 4; ++ni)
    wr[0][ni] = *(const bf16x8*)(wbase + ni * 8192);
  eb[0][0] = *(const bf16x8*)(abase + 32);
  eb[0][1] = *(const bf16x8*)(abase + 40);
  ((bf16x8*)Xs[0])[c0 * 128 + ar] = eb[1][0];
  ((bf16x8*)Xs[0])[(c0 + 1) * 128 + ar] = eb[1][1];
  eb[1][0] = *(const bf16x8*)(abase + 64);
  eb[1][1] = *(const bf16x8*)(abase + 72);
  BAR_LGKM();

#pragma unroll
  for (int ks = 0; ks < 16; ++ks) {
    const int p = ks & 1;
    bf16x8 af[8];
#pragma unroll
    for (int mi = 0; mi < 8; ++mi)
      af[mi] = ((const bf16x8*)Xs[p])[quad * 128 + mi * 16 + l15];
    if (ks < 15) {
      ((bf16x8*)Xs[p ^ 1])[c0 * 128 + ar] = eb[p][0];
      ((bf16x8*)Xs[p ^ 1])[(c0 + 1) * 128 + ar] = eb[p][1];
#pragma unroll
      for (int ni = 0; ni < 4; ++ni)
        wr[p ^ 1][ni] = *(const bf16x8*)(wbase + ni * 8192 + (ks + 1) * 32);
      if (ks < 13) {
        eb[p][0] = *(const bf16x8*)(abase + (ks + 3) * 32);
        eb[p][1] = *(const bf16x8*)(abase + (ks + 3) * 32 + 8);
      }
    }
#pragma unroll
    for (int mi = 0; mi < 8; ++mi)
#pragma unroll
      for (int ni = 0; ni < 4; ++ni)
        acc[mi][ni] = MFMA_BF16(af[mi], wr[p][ni], acc[mi][ni], 0, 0, 0);
    if (ks < 15) BAR_LGKM();
  }

#pragma unroll
  for (int mi = 0; mi < 8; ++mi)
#pragma unroll
    for (int ni = 0; ni < 4; ++ni) {
      const int col = n0 + ni * 16 + l15;
#pragma unroll
      for (int r = 0; r < 4; ++r) {
        const int row = m0 + mi * 16 + quad * 4 + r;
        out[(size_t)row * 512 + col] = acc[mi][ni][r];
      }
    }
}

extern "C" void kernel_launch(void* const* d_in, const int* in_sizes, int n_in,
                              void* d_out, int out_size, void* d_ws,
                              size_t ws_size, hipStream_t stream) {
  const float* xq = (const float*)d_in[0];
  const float* xk = (const float*)d_in[1];
  const float* xv = (const float*)d_in[2];
  const float* Wq = (const float*)d_in[3];
  const float* bq = (const float*)d_in[4];
  const float* Wk = (const float*)d_in[5];
  const float* bk = (const float*)d_in[6];
  const float* Wv = (const float*)d_in[7];
  const float* bv = (const float*)d_in[8];
  float* out = (float*)d_out;

  char* ws = (char*)d_ws;
  bf16_t* Eq = (bf16_t*)(ws + 0);           // 8x4096x512 bf16  33,554,432 B
  bf16_t* Ft = (bf16_t*)(ws + 33554432);    // 8x512x4096 bf16 (F transposed)
  bf16_t* Vt = (bf16_t*)(ws + 67108864);    // 8x512x4096 bf16 (V transposed)
  float* Bmp = (float*)(ws + 100663296);    // S x 8x512x512 f32 split-K partials

  // split-K=4 needs Bmp 33.5 MB -> Wt/Sq/Sk shift up; guard on ws_size.
  const int S = (ws_size >= (size_t)135823360) ? 4 : 2;
  const size_t wt_off = (S == 4) ? (size_t)134217728 : (size_t)117440512;
  bf16_t* Wt = (bf16_t*)(ws + wt_off);                  // 3x512x512 bf16
  float* Sq = (float*)(ws + wt_off + 1572864);          // 8x512 f32
  float* Sk = (float*)(ws + wt_off + 1572864 + 16384);  // 8x512 f32
  bf16_t* Ct = (bf16_t*)(ws + 33554432);    // aliases Ft (dead after bm_gemm)

  hipMemsetAsync(Sq, 0, 16384, stream);  // Sq atomic target only

  wt_kernel<<<dim3(8, 8, 3), 256, 0, stream>>>(Wq, Wk, Wv, Wt);
  proj_q<<<dim3(256, 2), 256, 0, stream>>>(xq, Wt, bq, Eq, Sq);
  proj_kv<<<dim3(256, 2, 2), 256, 0, stream>>>(xk, xv, Wt, bk, bv, Ft, Vt);
  sk_kernel<<<dim3(1024), 256, 0, stream>>>(Ft, Sk);
  bm_gemm<<<dim3(4, 4, 8 * S), 256, 0, stream>>>(Ft, Vt, Bmp, S);
  scale_kernel<<<dim3(8, 8, 8), 256, 0, stream>>>(Bmp, Sq, Sk, Ct, S);
  z_gemm<<<dim3(256, 2), 256, 0, stream>>>(Eq, Ct, out);
}

// Round 2
// 357.183 us; speedup vs baseline: 1.0912x; 1.0583x over previous
//
#include <hip/hip_runtime.h>
#include <hip/hip_bf16.h>

// LightAttention: Z = softmax_n(Q/d4) @ [ softmax_n(K/d4)^T @ V ]
// Folded: E=exp(Q/d4), F=exp(K/d4), Sq/Sk col-sums over n,
//   Bm[d,e] = sum_n F[n,d] V[n,e];  Ct[e,d] = Bm[d,e]/(Sq[d]Sk[d]);  Z = E @ Ct^T.
//
// Round-6: fully line-coalesced staging everywhere.
//  - proj_q/proj_kv: X fp32 loads remapped so each wave instr reads 8 rows x
//    128B full lines (was 32 rows x 16B partial lines -> MSHR thrash).
//    LDS chunk-major with 132-unit padded chunk stride (writes 2-way, reads free).
//  - z_gemm/bm_gemm: global_load_lds staging, row-major [128][64] LDS with
//    piece-XOR swizzle (piece ^= row&7) applied via pre-swizzled global source;
//    K_STEP=64. Each instr = 8 rows x 128B coalesced; frag reads 2-way free.
//  - B-operands (Wt/Ct) stay per-lane direct-to-reg (L2-resident).

typedef __bf16 bf16_t;
typedef __attribute__((ext_vector_type(8))) __bf16 bf16x8;
typedef __attribute__((ext_vector_type(4))) __bf16 bf16x4;
typedef __attribute__((ext_vector_type(4))) float f32x4;

#define MFMA_BF16 __builtin_amdgcn_mfma_f32_16x16x32_bf16

__device__ inline void async_ld16(const void* g, void* l) {
  __builtin_amdgcn_global_load_lds(
      (const __attribute__((address_space(1))) void*)g,
      (__attribute__((address_space(3))) void*)l, 16, 0, 0);
}

#define INV_D4 0.2102241038134287f  // 1 / 512^0.25

// Barrier that does NOT drain vmcnt (reg prefetches stay in flight).
#define BAR_LGKM()                                        \
  do {                                                    \
    asm volatile("s_waitcnt lgkmcnt(0)" ::: "memory");    \
    __builtin_amdgcn_s_barrier();                         \
  } while (0)

// Barrier for global_load_lds staging: drain vm + lgkm.
#define BAR_VM_LGKM()                                             \
  do {                                                            \
    asm volatile("s_waitcnt vmcnt(0) lgkmcnt(0)" ::: "memory");   \
    __builtin_amdgcn_s_barrier();                                 \
  } while (0)

// Store 4 float4 (rows xr+32i, piece f4) into padded chunk-major LDS.
// Unit (c,row) at elem (c*132+row)*8; this thread owns half `half` (8B).
__device__ inline void cvt_store4(bf16_t* dst, const float4* f, int cch,
                                  int xr, int half) {
#pragma unroll
  for (int i = 0; i < 4; ++i) {
    bf16x4 v;
    v[0] = (__bf16)f[i].x; v[1] = (__bf16)f[i].y;
    v[2] = (__bf16)f[i].z; v[3] = (__bf16)f[i].w;
    *(bf16x4*)(dst + (size_t)(cch * 132 + xr + 32 * i) * 8 + half * 4) = v;
  }
}

// ---------------- W transpose+convert: W[in][out] f32 -> Wt[out][in] bf16 ----
__global__ __launch_bounds__(256) void wt_kernel(
    const float* __restrict__ Wq, const float* __restrict__ Wk,
    const float* __restrict__ Wv, bf16_t* __restrict__ Wt) {
  const int z = blockIdx.z;
  const float* W = (z == 0) ? Wq : (z == 1) ? Wk : Wv;
  bf16_t* O = Wt + (size_t)z * 262144;
  __shared__ __align__(16) bf16_t tile[64 * 72];
  const int t = threadIdx.x;
  const int r = t >> 2;
  const int c4 = (t & 3) * 16;
  const int in0 = blockIdx.x * 64, out0 = blockIdx.y * 64;
  const float* src = W + (size_t)(in0 + r) * 512 + out0 + c4;
#pragma unroll
  for (int i = 0; i < 4; ++i) {
    float4 f = ((const float4*)src)[i];
    tile[(c4 + i * 4 + 0) * 72 + r] = (__bf16)f.x;
    tile[(c4 + i * 4 + 1) * 72 + r] = (__bf16)f.y;
    tile[(c4 + i * 4 + 2) * 72 + r] = (__bf16)f.z;
    tile[(c4 + i * 4 + 3) * 72 + r] = (__bf16)f.w;
  }
  __syncthreads();
  bf16x8* dst = (bf16x8*)(O + (size_t)(out0 + r) * 512 + in0 + c4);
  const bf16x8* s = (const bf16x8*)(tile + r * 72 + c4);
  dst[0] = s[0];
  dst[1] = s[1];
}

// ---------------- proj_q: Eq[n][d]=exp((Xq@Wq+b)/d4), 128x256 tiles ---------
__global__ __launch_bounds__(256, 2) void proj_q(
    const float* __restrict__ Xq, const bf16_t* __restrict__ Wt,
    const float* __restrict__ bias, bf16_t* __restrict__ Eq,
    float* __restrict__ Sq) {
  __shared__ __align__(16) bf16_t Xs[2][4224];  // 4 chunks x 132 units x 8

  const int t = threadIdx.x;
  const int lane = t & 63, w = t >> 6;
  const int quad = lane >> 4, l15 = lane & 15;
  const int m0 = blockIdx.x * 128;
  const int n0 = blockIdx.y * 256 + w * 64;  // per-wave col base

  f32x4 acc[8][4];
  const f32x4 zero4 = {0.f, 0.f, 0.f, 0.f};
#pragma unroll
  for (int i = 0; i < 8; ++i)
#pragma unroll
    for (int j = 0; j < 4; ++j) acc[i][j] = zero4;

  // Coalesced X mapping: thread t loads rows (t>>3)+32i, piece t&7.
  const int xr = t >> 3;
  const int f4 = t & 7;
  const int cch = f4 >> 1, half = f4 & 1;
  const float* abase = Xq + (size_t)(m0 + xr) * 512 + f4 * 4;
  const bf16_t* wbase = Wt + (size_t)(n0 + l15) * 512 + quad * 8;

  float4 fb[2][4];   // X fp32 prefetch, 2 steps deep
  bf16x8 wr[2][4];   // W fragment regs, 1 step deep

#pragma unroll
  for (int i = 0; i < 4; ++i) fb[1][i] = *(const float4*)(abase + i * 16384);
#pragma unroll
  for (int ni = 0; ni < 4; ++ni)
    wr[0][ni] = *(const bf16x8*)(wbase + ni * 8192);
#pragma unroll
  for (int i = 0; i < 4; ++i)
    fb[0][i] = *(const float4*)(abase + i * 16384 + 32);
  cvt_store4(Xs[0], fb[1], cch, xr, half);
#pragma unroll
  for (int i = 0; i < 4; ++i)
    fb[1][i] = *(const float4*)(abase + i * 16384 + 64);
  BAR_LGKM();

#pragma unroll
  for (int ks = 0; ks < 16; ++ks) {
    const int p = ks & 1;
    bf16x8 af[8];
#pragma unroll
    for (int mi = 0; mi < 8; ++mi)
      af[mi] = *(const bf16x8*)(&Xs[p][(size_t)(quad * 132 + mi * 16 + l15) * 8]);
    if (ks < 15) {
      cvt_store4(Xs[p ^ 1], fb[p], cch, xr, half);
#pragma unroll
      for (int ni = 0; ni < 4; ++ni)
        wr[p ^ 1][ni] = *(const bf16x8*)(wbase + ni * 8192 + (ks + 1) * 32);
      if (ks < 13) {
#pragma unroll
        for (int i = 0; i < 4; ++i)
          fb[p][i] = *(const float4*)(abase + i * 16384 + (ks + 3) * 32);
      }
    }
#pragma unroll
    for (int mi = 0; mi < 8; ++mi)
#pragma unroll
      for (int ni = 0; ni < 4; ++ni)
        acc[mi][ni] = MFMA_BF16(af[mi], wr[p][ni], acc[mi][ni], 0, 0, 0);
    if (ks < 15) BAR_LGKM();
  }

  const int b = m0 >> 12;
  float cs[4] = {0.f, 0.f, 0.f, 0.f};
#pragma unroll
  for (int ni = 0; ni < 4; ++ni) {
    const int col = n0 + ni * 16 + l15;
    const float bv_ = bias[col];
#pragma unroll
    for (int mi = 0; mi < 8; ++mi)
#pragma unroll
      for (int r = 0; r < 4; ++r) {
        const int row = m0 + mi * 16 + quad * 4 + r;
        float v = __expf((acc[mi][ni][r] + bv_) * INV_D4);
        Eq[(size_t)row * 512 + col] = (bf16_t)v;
        cs[ni] += v;
      }
  }
#pragma unroll
  for (int ni = 0; ni < 4; ++ni) {
    cs[ni] += __shfl_xor(cs[ni], 16);
    cs[ni] += __shfl_xor(cs[ni], 32);
  }
  if (lane < 16) {
#pragma unroll
    for (int ni = 0; ni < 4; ++ni)
      atomicAdd(&Sq[b * 512 + n0 + ni * 16 + lane], cs[ni]);
  }
}

// ---------------- proj_kv: Ft/Vt[b][d][n], 256(d)x128(n) tiles --------------
__global__ __launch_bounds__(256, 2) void proj_kv(
    const float* __restrict__ xk, const float* __restrict__ xv,
    const bf16_t* __restrict__ Wt, const float* __restrict__ bk,
    const float* __restrict__ bv, bf16_t* __restrict__ Ft,
    bf16_t* __restrict__ Vt) {
  const int z = blockIdx.z + 1;  // 1=K, 2=V
  const float* X = (z == 1) ? xk : xv;
  const float* bias = (z == 1) ? bk : bv;
  const bf16_t* W = Wt + (size_t)z * 262144;
  bf16_t* Out = (z == 1) ? Ft : Vt;
  const bool expm = (z == 1);

  __shared__ __align__(16) bf16_t Xs[2][4224];

  const int t = threadIdx.x;
  const int lane = t & 63, w = t >> 6;
  const int quad = lane >> 4, l15 = lane & 15;
  const int ng = blockIdx.x * 128;             // global n over 32768
  const int d0 = blockIdx.y * 256 + w * 64;    // per-wave d base

  f32x4 acc[4][8];
  const f32x4 zero4 = {0.f, 0.f, 0.f, 0.f};
#pragma unroll
  for (int i = 0; i < 4; ++i)
#pragma unroll
    for (int j = 0; j < 8; ++j) acc[i][j] = zero4;

  const int xr = t >> 3;
  const int f4 = t & 7;
  const int cch = f4 >> 1, half = f4 & 1;
  const float* bbase = X + (size_t)(ng + xr) * 512 + f4 * 4;
  const bf16_t* wbase = W + (size_t)(d0 + l15) * 512 + quad * 8;

  float4 fb[2][4];
  bf16x8 wr[2][4];

#pragma unroll
  for (int i = 0; i < 4; ++i) fb[1][i] = *(const float4*)(bbase + i * 16384);
#pragma unroll
  for (int mi = 0; mi < 4; ++mi)
    wr[0][mi] = *(const bf16x8*)(wbase + mi * 8192);
#pragma unroll
  for (int i = 0; i < 4; ++i)
    fb[0][i] = *(const float4*)(bbase + i * 16384 + 32);
  cvt_store4(Xs[0], fb[1], cch, xr, half);
#pragma unroll
  for (int i = 0; i < 4; ++i)
    fb[1][i] = *(const float4*)(bbase + i * 16384 + 64);
  BAR_LGKM();

#pragma unroll
  for (int ks = 0; ks < 16; ++ks) {
    const int p = ks & 1;
    bf16x8 bx[8];
#pragma unroll
    for (int ni = 0; ni < 8; ++ni)
      bx[ni] = *(const bf16x8*)(&Xs[p][(size_t)(quad * 132 + ni * 16 + l15) * 8]);
    if (ks < 15) {
      cvt_store4(Xs[p ^ 1], fb[p], cch, xr, half);
#pragma unroll
      for (int mi = 0; mi < 4; ++mi)
        wr[p ^ 1][mi] = *(const bf16x8*)(wbase + mi * 8192 + (ks + 1) * 32);
      if (ks < 13) {
#pragma unroll
        for (int i = 0; i < 4; ++i)
          fb[p][i] = *(const float4*)(bbase + i * 16384 + (ks + 3) * 32);
      }
    }
#pragma unroll
    for (int mi = 0; mi < 4; ++mi)
#pragma unroll
      for (int ni = 0; ni < 8; ++ni)
        acc[mi][ni] = MFMA_BF16(wr[p][mi], bx[ni], acc[mi][ni], 0, 0, 0);
    if (ks < 15) BAR_LGKM();
  }

  const int b = ng >> 12;
  const int nl0 = (ng & 4095);
#pragma unroll
  for (int mi = 0; mi < 4; ++mi)
#pragma unroll
    for (int r = 0; r < 4; ++r) {
      const int d = d0 + mi * 16 + quad * 4 + r;
      const float bv_ = bias[d];
      bf16_t* rowp = Out + (size_t)b * 2097152 + (size_t)d * 4096 + nl0;
#pragma unroll
      for (int ni = 0; ni < 8; ++ni) {
        float v = acc[mi][ni][r] + bv_;
        if (expm) v = __expf(v * INV_D4);
        rowp[ni * 16 + l15] = (bf16_t)v;
      }
    }
}

// ---------------- Sk[b*512+d] = sum_n Ft[b][d][n] (row sums) ----------------
__global__ __launch_bounds__(256) void sk_kernel(const bf16_t* __restrict__ Ft,
                                                 float* __restrict__ Sk) {
  const int row = blockIdx.x * 4 + (threadIdx.x >> 6);
  const int lane = threadIdx.x & 63;
  const bf16x8* p = (const bf16x8*)(Ft + (size_t)row * 4096) + lane;
  float s = 0.f;
#pragma unroll
  for (int j = 0; j < 8; ++j) {
    bf16x8 v = p[j * 64];
#pragma unroll
    for (int e = 0; e < 8; ++e) s += (float)v[e];
  }
#pragma unroll
  for (int m = 1; m <= 32; m <<= 1) s += __shfl_xor(s, m);
  if (lane == 0) Sk[row] = s;
}

// ---------------- Bm GEMM: Bmp[s][b][d][e] = sum_{n in slice} Ft[d][n]Vt[e][n]
// Row-major swizzled LDS staging, K_STEP=64, coalesced 8-rows-per-instr loads.
__global__ __launch_bounds__(256, 2) void bm_gemm(
    const bf16_t* __restrict__ Ft, const bf16_t* __restrict__ Vt,
    float* __restrict__ Bmp, int S) {
  const int b = blockIdx.z / S;
  const int s = blockIdx.z - b * S;
  const int d0 = blockIdx.x * 128;
  const int e0 = blockIdx.y * 128;
  const bf16_t* A = Ft + (size_t)b * 2097152;
  const bf16_t* B = Vt + (size_t)b * 2097152;
  float* out = Bmp + ((size_t)s * 8 + b) * 262144;

  __shared__ __align__(16) bf16_t As[2][8192];  // row-major [128][64], swizzled
  __shared__ __align__(16) bf16_t Bs[2][8192];

  const int t = threadIdx.x;
  const int lane = t & 63, w = t >> 6;
  const int quad = lane >> 4, l15 = lane & 15;
  const int m_off = (w & 1) * 64, n_off = (w >> 1) * 64;

  const int kper = 4096 / S;
  const int KS = kper >> 6;  // K_STEP = 64
  const int kbase = s * kper;

  f32x4 acc[4][4];
  const f32x4 zero4 = {0.f, 0.f, 0.f, 0.f};
#pragma unroll
  for (int i = 0; i < 4; ++i)
#pragma unroll
    for (int j = 0; j < 4; ++j) acc[i][j] = zero4;

  const int srow = lane >> 3;                 // 0..7
  const int spiece = (lane & 7) ^ srow;       // pre-swizzled global piece
  const bf16_t* asrc = A + (size_t)(d0 + srow) * 4096 + kbase + spiece * 8;
  const bf16_t* bsrc = B + (size_t)(e0 + srow) * 4096 + kbase + spiece * 8;
  const int q0 = w * 4;
  const int rsw = l15 & 7;

  auto stage = [&](int buf, int ks) {
#pragma unroll
    for (int i = 0; i < 4; ++i) {
      const int q = q0 + i;
      async_ld16(asrc + (size_t)q * 8 * 4096 + ks * 64, &As[buf][q * 512]);
      async_ld16(bsrc + (size_t)q * 8 * 4096 + ks * 64, &Bs[buf][q * 512]);
    }
  };

  stage(0, 0);
  BAR_VM_LGKM();

  for (int ks = 0; ks < KS; ++ks) {
    const int p = ks & 1;
    if (ks + 1 < KS) stage(p ^ 1, ks + 1);
#pragma unroll
    for (int ksub = 0; ksub < 2; ++ksub) {
      const int c = ksub * 4 + quad;
      bf16x8 af[4], bfr[4];
#pragma unroll
      for (int mi = 0; mi < 4; ++mi) {
        const int row = m_off + mi * 16 + l15;
        af[mi] = *(const bf16x8*)(&As[p][(size_t)row * 64 + ((c ^ rsw) << 3)]);
      }
#pragma unroll
      for (int ni = 0; ni < 4; ++ni) {
        const int row = n_off + ni * 16 + l15;
        bfr[ni] = *(const bf16x8*)(&Bs[p][(size_t)row * 64 + ((c ^ rsw) << 3)]);
      }
#pragma unroll
      for (int mi = 0; mi < 4; ++mi)
#pragma unroll
        for (int ni = 0; ni < 4; ++ni)
          acc[mi][ni] = MFMA_BF16(af[mi], bfr[ni], acc[mi][ni], 0, 0, 0);
    }
    if (ks + 1 < KS) BAR_VM_LGKM();
  }

#pragma unroll
  for (int mi = 0; mi < 4; ++mi)
#pragma unroll
    for (int ni = 0; ni < 4; ++ni) {
      const int ecol = e0 + n_off + ni * 16 + l15;
#pragma unroll
      for (int r = 0; r < 4; ++r) {
        const int drow = d0 + m_off + mi * 16 + quad * 4 + r;
        out[(size_t)drow * 512 + ecol] = acc[mi][ni][r];
      }
    }
}

// ---------------- scale + reduce partials + transpose -----------------------
__global__ __launch_bounds__(256) void scale_kernel(
    const float* __restrict__ Bmp, const float* __restrict__ Sq,
    const float* __restrict__ Sk, bf16_t* __restrict__ Ct, int S) {
  const int b = blockIdx.z;
  const int d0 = blockIdx.x * 64, e0 = blockIdx.y * 64;
  __shared__ __align__(16) bf16_t tile[64 * 72];
  const int t = threadIdx.x;
  const int r = t >> 2;
  const int c4 = (t & 3) * 16;
  const int d = d0 + r;
  const float f = 1.0f / (Sq[b * 512 + d] * Sk[b * 512 + d]);
  const float* p0 = Bmp + (size_t)b * 262144 + (size_t)d * 512 + e0 + c4;
#pragma unroll
  for (int i = 0; i < 4; ++i) {
    float sx = 0.f, sy = 0.f, sz = 0.f, sw = 0.f;
    for (int sp = 0; sp < S; ++sp) {
      float4 v = ((const float4*)(p0 + (size_t)sp * 2097152))[i];
      sx += v.x; sy += v.y; sz += v.z; sw += v.w;
    }
    tile[(c4 + i * 4 + 0) * 72 + r] = (__bf16)(sx * f);
    tile[(c4 + i * 4 + 1) * 72 + r] = (__bf16)(sy * f);
    tile[(c4 + i * 4 + 2) * 72 + r] = (__bf16)(sz * f);
    tile[(c4 + i * 4 + 3) * 72 + r] = (__bf16)(sw * f);
  }
  __syncthreads();
  bf16x8* dst = (bf16x8*)(Ct + (size_t)b * 262144 + (size_t)(e0 + r) * 512 + d0 + c4);
  const bf16x8* sptr = (const bf16x8*)(tile + r * 72 + c4);
  dst[0] = sptr[0];
  dst[1] = sptr[1];
}

// ---------------- Z GEMM: Z[row,e]=sum_d Eq[row,d]*Ct[b][e][d], 128x256 -----
// A = Eq via swizzled row-major gload_lds (K_STEP=64); B = Ct direct to regs.
__global__ __launch_bounds__(256, 2) void z_gemm(
    const bf16_t* __restrict__ Eq, const bf16_t* __restrict__ Ct,
    float* __restrict__ out) {
  __shared__ __align__(16) bf16_t As[2][8192];  // row-major [128][64], swizzled

  const int t = threadIdx.x;
  const int lane = t & 63, w = t >> 6;
  const int quad = lane >> 4, l15 = lane & 15;
  const int m0 = blockIdx.x * 128;
  const int n0 = blockIdx.y * 256 + w * 64;
  const int batch = m0 >> 12;
  const bf16_t* Bt = Ct + (size_t)batch * 262144;

  f32x4 acc[8][4];
  const f32x4 zero4 = {0.f, 0.f, 0.f, 0.f};
#pragma unroll
  for (int i = 0; i < 8; ++i)
#pragma unroll
    for (int j = 0; j < 4; ++j) acc[i][j] = zero4;

  const int srow = lane >> 3;
  const int spiece = (lane & 7) ^ srow;
  const bf16_t* asrc = Eq + (size_t)(m0 + srow) * 512 + spiece * 8;
  const int q0 = w * 4;
  const int rsw = l15 & 7;
  const bf16_t* wbase = Bt + (size_t)(n0 + l15) * 512 + quad * 8;

  auto stageZ = [&](int buf, int ks) {
#pragma unroll
    for (int i = 0; i < 4; ++i) {
      const int q = q0 + i;
      async_ld16(asrc + (size_t)q * 8 * 512 + ks * 64, &As[buf][q * 512]);
    }
  };

  stageZ(0, 0);
  BAR_VM_LGKM();

#pragma unroll
  for (int ks = 0; ks < 8; ++ks) {
    const int p = ks & 1;
    if (ks < 7) stageZ(p ^ 1, ks + 1);
    bf16x8 wrA[4], wrB[4];
#pragma unroll
    for (int ni = 0; ni < 4; ++ni) {
      wrA[ni] = *(const bf16x8*)(wbase + ni * 8192 + ks * 64);
      wrB[ni] = *(const bf16x8*)(wbase + ni * 8192 + ks * 64 + 32);
    }
#pragma unroll
    for (int ksub = 0; ksub < 2; ++ksub) {
      const int c = ksub * 4 + quad;
      bf16x8 af[8];
#pragma unroll
      for (int mi = 0; mi < 8; ++mi) {
        const int row = mi * 16 + l15;
        af[mi] = *(const bf16x8*)(&As[p][(size_t)row * 64 + ((c ^ rsw) << 3)]);
      }
#pragma unroll
      for (int mi = 0; mi < 8; ++mi)
#pragma unroll
        for (int ni = 0; ni < 4; ++ni)
          acc[mi][ni] =
              MFMA_BF16(af[mi], ksub ? wrB[ni] : wrA[ni], acc[mi][ni], 0, 0, 0);
    }
    if (ks < 7) BAR_VM_LGKM();
  }

#pragma unroll
  for (int mi = 0; mi < 8; ++mi)
#pragma unroll
    for (int ni = 0; ni < 4; ++ni) {
      const int col = n0 + ni * 16 + l15;
#pragma unroll
      for (int r = 0; r < 4; ++r) {
        const int row = m0 + mi * 16 + quad * 4 + r;
        out[(size_t)row * 512 + col] = acc[mi][ni][r];
      }
    }
}

extern "C" void kernel_launch(void* const* d_in, const int* in_sizes, int n_in,
                              void* d_out, int out_size, void* d_ws,
                              size_t ws_size, hipStream_t stream) {
  const float* xq = (const float*)d_in[0];
  const float* xk = (const float*)d_in[1];
  const float* xv = (const float*)d_in[2];
  const float* Wq = (const float*)d_in[3];
  const float* bq = (const float*)d_in[4];
  const float* Wk = (const float*)d_in[5];
  const float* bk = (const float*)d_in[6];
  const float* Wv = (const float*)d_in[7];
  const float* bv = (const float*)d_in[8];
  float* out = (float*)d_out;

  char* ws = (char*)d_ws;
  bf16_t* Eq = (bf16_t*)(ws + 0);           // 8x4096x512 bf16  33,554,432 B
  bf16_t* Ft = (bf16_t*)(ws + 33554432);    // 8x512x4096 bf16 (F transposed)
  bf16_t* Vt = (bf16_t*)(ws + 67108864);    // 8x512x4096 bf16 (V transposed)
  float* Bmp = (float*)(ws + 100663296);    // S x 8x512x512 f32 split-K partials

  const int S = (ws_size >= (size_t)135823360) ? 4 : 2;
  const size_t wt_off = (S == 4) ? (size_t)134217728 : (size_t)117440512;
  bf16_t* Wt = (bf16_t*)(ws + wt_off);                  // 3x512x512 bf16
  float* Sq = (float*)(ws + wt_off + 1572864);          // 8x512 f32
  float* Sk = (float*)(ws + wt_off + 1572864 + 16384);  // 8x512 f32
  bf16_t* Ct = (bf16_t*)(ws + 33554432);    // aliases Ft (dead after bm_gemm)

  hipMemsetAsync(Sq, 0, 16384, stream);  // Sq atomic target only

  wt_kernel<<<dim3(8, 8, 3), 256, 0, stream>>>(Wq, Wk, Wv, Wt);
  proj_q<<<dim3(256, 2), 256, 0, stream>>>(xq, Wt, bq, Eq, Sq);
  proj_kv<<<dim3(256, 2, 2), 256, 0, stream>>>(xk, xv, Wt, bk, bv, Ft, Vt);
  sk_kernel<<<dim3(1024), 256, 0, stream>>>(Ft, Sk);
  bm_gemm<<<dim3(4, 4, 8 * S), 256, 0, stream>>>(Ft, Vt, Bmp, S);
  scale_kernel<<<dim3(8, 8, 8), 256, 0, stream>>>(Bmp, Sq, Sk, Ct, S);
  z_gemm<<<dim3(256, 2), 256, 0, stream>>>(Eq, Ct, out);
}